// Round 2
// baseline (437.123 us; speedup 1.0000x reference)
//
#include <hip/hip_runtime.h>

// 3D Haar DWT, level 1, zero-pad (exact pairwise), fp32.
// x: [B=2, C=32, D=64, H=128, W=128] -> out: [B, 8C, D/2, H/2, W/2]
// Subband order along channel: s = sz*4 + sy*2 + sx (depth, height, width high-pass bits).
//
// v2b: 4 output dx per thread -> 2x 16B loads per row (32 B/lane) and 16B
// stores (1 KiB per wave-store vs 512 B with float2), plus nontemporal
// load/store hints (512 MiB streaming footprint = 2x L3; neither stream is
// ever re-read, so cache allocation is pure churn). Uses clang
// ext_vector_type since __builtin_nontemporal_* rejects HIP_vector_type.

#define B_N 2
#define C_N 32
#define D_N 64
#define H_N 128
#define W_N 128
#define DH (D_N / 2)
#define HH (H_N / 2)
#define WH (W_N / 2)

typedef float f32x4 __attribute__((ext_vector_type(4)));

__global__ __launch_bounds__(256) void haar3d_kernel(const float* __restrict__ x,
                                                     float* __restrict__ out) {
    const float SCALE = 0.35355339059327373f;  // (1/sqrt(2))^3

    // tid bits: [b:1][c:5][dz:5][dy:6][wo:4]  (total 2^21 threads)
    int tid = blockIdx.x * 256 + threadIdx.x;
    int wo = tid & 15;          // W/8 chunk index (covers output dx = 4*wo .. 4*wo+3)
    int dy = (tid >> 4) & 63;   // HH
    int dz = (tid >> 10) & 31;  // DH
    int c  = (tid >> 15) & 31;  // C
    int b  = (tid >> 20);       // B

    size_t in_base = ((((size_t)(b * C_N + c) * D_N + 2 * dz) * H_N + 2 * dy) * W_N + 8 * wo);
    const float* p0 = x + in_base;                      // z0,y0
    const float* p1 = p0 + W_N;                         // z0,y1
    const float* p2 = p0 + (size_t)H_N * W_N;           // z1,y0
    const float* p3 = p2 + W_N;                         // z1,y1

    f32x4 r0a = __builtin_nontemporal_load((const f32x4*)p0);
    f32x4 r0b = __builtin_nontemporal_load((const f32x4*)(p0 + 4));
    f32x4 r1a = __builtin_nontemporal_load((const f32x4*)p1);
    f32x4 r1b = __builtin_nontemporal_load((const f32x4*)(p1 + 4));
    f32x4 r2a = __builtin_nontemporal_load((const f32x4*)p2);
    f32x4 r2b = __builtin_nontemporal_load((const f32x4*)(p2 + 4));
    f32x4 r3a = __builtin_nontemporal_load((const f32x4*)p3);
    f32x4 r3b = __builtin_nontemporal_load((const f32x4*)(p3 + 4));

    // Width-axis lo/hi per row, four output positions j=0..3
    float L0[4], L1[4], L2[4], L3[4];
    float H0[4], H1[4], H2[4], H3[4];
    L0[0] = r0a.x + r0a.y; L0[1] = r0a.z + r0a.w; L0[2] = r0b.x + r0b.y; L0[3] = r0b.z + r0b.w;
    H0[0] = r0a.x - r0a.y; H0[1] = r0a.z - r0a.w; H0[2] = r0b.x - r0b.y; H0[3] = r0b.z - r0b.w;
    L1[0] = r1a.x + r1a.y; L1[1] = r1a.z + r1a.w; L1[2] = r1b.x + r1b.y; L1[3] = r1b.z + r1b.w;
    H1[0] = r1a.x - r1a.y; H1[1] = r1a.z - r1a.w; H1[2] = r1b.x - r1b.y; H1[3] = r1b.z - r1b.w;
    L2[0] = r2a.x + r2a.y; L2[1] = r2a.z + r2a.w; L2[2] = r2b.x + r2b.y; L2[3] = r2b.z + r2b.w;
    H2[0] = r2a.x - r2a.y; H2[1] = r2a.z - r2a.w; H2[2] = r2b.x - r2b.y; H2[3] = r2b.z - r2b.w;
    L3[0] = r3a.x + r3a.y; L3[1] = r3a.z + r3a.w; L3[2] = r3b.x + r3b.y; L3[3] = r3b.z + r3b.w;
    H3[0] = r3a.x - r3a.y; H3[1] = r3a.z - r3a.w; H3[2] = r3b.x - r3b.y; H3[3] = r3b.z - r3b.w;

    // Output base for subband 0; subbands are C*DH*HH*WH apart along channel dim
    size_t ob = ((((size_t)(b * 8) * C_N + c) * DH + dz) * HH + dy) * WH + 4 * wo;
    const size_t SSTRIDE = (size_t)C_N * DH * HH * WH;  // 4,194,304 floats

    f32x4 s0, s1, s2, s3, s4, s5, s6, s7;

#pragma unroll
    for (int j = 0; j < 4; ++j) {
        // height-axis butterfly
        float tL0 = L0[j] + L1[j];  // y-low  @ z0
        float tL1 = L0[j] - L1[j];  // y-high @ z0
        float tL2 = L2[j] + L3[j];  // y-low  @ z1
        float tL3 = L2[j] - L3[j];  // y-high @ z1
        float tH0 = H0[j] + H1[j];
        float tH1 = H0[j] - H1[j];
        float tH2 = H2[j] + H3[j];
        float tH3 = H2[j] - H3[j];
        // depth-axis butterfly; s = sz*4 + sy*2 + sx
        s0[j] = (tL0 + tL2) * SCALE;  // aaa
        s1[j] = (tH0 + tH2) * SCALE;  // aad
        s2[j] = (tL1 + tL3) * SCALE;  // ada
        s3[j] = (tH1 + tH3) * SCALE;  // add
        s4[j] = (tL0 - tL2) * SCALE;  // daa
        s5[j] = (tH0 - tH2) * SCALE;  // dad
        s6[j] = (tL1 - tL3) * SCALE;  // dda
        s7[j] = (tH1 - tH3) * SCALE;  // ddd
    }

    __builtin_nontemporal_store(s0, (f32x4*)(out + ob + 0 * SSTRIDE));
    __builtin_nontemporal_store(s1, (f32x4*)(out + ob + 1 * SSTRIDE));
    __builtin_nontemporal_store(s2, (f32x4*)(out + ob + 2 * SSTRIDE));
    __builtin_nontemporal_store(s3, (f32x4*)(out + ob + 3 * SSTRIDE));
    __builtin_nontemporal_store(s4, (f32x4*)(out + ob + 4 * SSTRIDE));
    __builtin_nontemporal_store(s5, (f32x4*)(out + ob + 5 * SSTRIDE));
    __builtin_nontemporal_store(s6, (f32x4*)(out + ob + 6 * SSTRIDE));
    __builtin_nontemporal_store(s7, (f32x4*)(out + ob + 7 * SSTRIDE));
}

extern "C" void kernel_launch(void* const* d_in, const int* in_sizes, int n_in,
                              void* d_out, int out_size, void* d_ws, size_t ws_size,
                              hipStream_t stream) {
    const float* x = (const float*)d_in[0];
    float* out = (float*)d_out;
    // total threads = B*C*DH*HH*(WH/4) = 2*32*32*64*16 = 2^21
    const int n_threads = B_N * C_N * DH * HH * (WH / 4);
    const int block = 256;
    const int grid = n_threads / block;  // 8192
    haar3d_kernel<<<grid, block, 0, stream>>>(x, out);
}